// Round 1
// baseline (466.651 us; speedup 1.0000x reference)
//
#include <hip/hip_runtime.h>

// Problem constants (fixed by reference setup_inputs)
#define B_     64
#define K_     4
#define M_     3
#define NPIX   65536      // X*Y = 256*256
#define CHUNKS 32         // blocks per image -> grid = 2048 = 8 blocks/CU
#define GRID_  (B_ * CHUNKS)
#define TPB    256
#define ITERS  2          // pixels/thread = ITERS*4 = 8
#define NV     16         // 4 den + 12 num partials per thread
#define KM     (K_ * M_)

// Single fused kernel: streaming masked reduction + last-block finalize.
__global__ __launch_bounds__(TPB) void fused_kernel(
    const float* __restrict__ pred,    // [B,K,NPIX]
    const float* __restrict__ inp,     // [B,M,NPIX]
    const int*   __restrict__ heart,   // [B,NPIX]
    const float* __restrict__ mu_data, // [K,M]
    float* __restrict__ num_ws,        // [B,K,M]
    float* __restrict__ den_ws,        // [B,K]
    unsigned int* __restrict__ counter,// [1], zeroed before launch
    float* __restrict__ out)           // [1]
{
    const int b     = blockIdx.x >> 5;           // / CHUNKS
    const int chunk = blockIdx.x & (CHUNKS - 1);

    // val[0..3] = den[k]; val[4 + k*3 + m] = num[k][m]
    float val[NV];
#pragma unroll
    for (int i = 0; i < NV; ++i) val[i] = 0.0f;

#pragma unroll
    for (int it = 0; it < ITERS; ++it) {
        const int pix = chunk * (NPIX / CHUNKS) + it * (TPB * 4) + (int)threadIdx.x * 4;

        const int4 h = *reinterpret_cast<const int4*>(heart + (size_t)b * NPIX + pix);
        float4 mask;
        mask.x = (h.x == 1) ? 1.0f : 0.0f;
        mask.y = (h.y == 1) ? 1.0f : 0.0f;
        mask.z = (h.z == 1) ? 1.0f : 0.0f;
        mask.w = (h.w == 1) ? 1.0f : 0.0f;

        float4 in[M_];
#pragma unroll
        for (int m = 0; m < M_; ++m)
            in[m] = *reinterpret_cast<const float4*>(inp + ((size_t)b * M_ + m) * NPIX + pix);

#pragma unroll
        for (int k = 0; k < K_; ++k) {
            float4 p = *reinterpret_cast<const float4*>(pred + ((size_t)b * K_ + k) * NPIX + pix);
            float4 pm;
            pm.x = p.x * mask.x; pm.y = p.y * mask.y;
            pm.z = p.z * mask.z; pm.w = p.w * mask.w;
            val[k] += (pm.x + pm.y) + (pm.z + pm.w);
#pragma unroll
            for (int m = 0; m < M_; ++m)
                val[4 + k * M_ + m] += pm.x * in[m].x + pm.y * in[m].y
                                     + pm.z * in[m].z + pm.w * in[m].w;
        }
    }

    // 4-stage butterfly (off 32..4): lanes 0..3 hold sums over lane≡l (mod 4).
    // Truncated vs full 6-stage: 64 DS ops instead of 96; LDS finishes the rest.
#pragma unroll
    for (int off = 32; off >= 4; off >>= 1) {
#pragma unroll
        for (int i = 0; i < NV; ++i)
            val[i] += __shfl_down(val[i], off, 64);
    }

    __shared__ float smem[TPB / 64][4][NV];
    const int lane = threadIdx.x & 63;
    const int wave = threadIdx.x >> 6;
    if (lane < 4) {
#pragma unroll
        for (int i = 0; i < NV; ++i) smem[wave][lane][i] = val[i];
    }
    __syncthreads();

    if (threadIdx.x < NV) {
        float s = 0.0f;
#pragma unroll
        for (int w = 0; w < TPB / 64; ++w)
#pragma unroll
            for (int l = 0; l < 4; ++l)
                s += smem[w][l][threadIdx.x];
        if (threadIdx.x < K_)
            atomicAdd(&den_ws[b * K_ + threadIdx.x], s);
        else
            atomicAdd(&num_ws[b * KM + (threadIdx.x - K_)], s);
    }

    // ---- grid-completion ticket; the last block to arrive finalizes ----
    __shared__ unsigned int ticket;
    __threadfence();              // release: this block's atomics visible device-wide
    __syncthreads();              // all fences done before tid0 signals
    if (threadIdx.x == 0)
        ticket = atomicAdd(counter, 1u);
    __syncthreads();
    if (ticket != GRID_ - 1) return;

    if (threadIdx.x < B_) {       // one wave: lane bb owns batch element bb
        __threadfence();          // acquire side
        const int bb = threadIdx.x;
        float r[KM];
#pragma unroll
        for (int k = 0; k < K_; ++k) {
            const float den = __hip_atomic_load(&den_ws[bb * K_ + k],
                                __ATOMIC_RELAXED, __HIP_MEMORY_SCOPE_AGENT) + 1e-10f;
            const float inv = 1.0f / den;
#pragma unroll
            for (int m = 0; m < M_; ++m)
                r[k * M_ + m] = __hip_atomic_load(&num_ws[bb * KM + k * M_ + m],
                                  __ATOMIC_RELAXED, __HIP_MEMORY_SCOPE_AGENT) * inv;
        }
#pragma unroll
        for (int off = 32; off > 0; off >>= 1) {
#pragma unroll
            for (int i = 0; i < KM; ++i)
                r[i] += __shfl_down(r[i], off, 64);
        }
        if (bb == 0) {
            float s = 0.0f;
#pragma unroll
            for (int i = 0; i < KM; ++i) {
                const float d = mu_data[i] - r[i] * (1.0f / (float)B_);
                s += d * d;
            }
            out[0] = s;
        }
    }
}

extern "C" void kernel_launch(void* const* d_in, const int* in_sizes, int n_in,
                              void* d_out, int out_size, void* d_ws, size_t ws_size,
                              hipStream_t stream) {
    const float* pred    = (const float*)d_in[0];  // [64,4,256,256] f32
    const float* inp     = (const float*)d_in[1];  // [64,3,256,256] f32
    const int*   heart   = (const int*)d_in[2];    // [64,1,256,256] i32
    const float* mu_data = (const float*)d_in[3];  // [4,3] f32
    float* out = (float*)d_out;

    float* num_ws = (float*)d_ws;                        // [B,K,M]
    float* den_ws = num_ws + B_ * KM;                    // [B,K]
    unsigned int* counter = (unsigned int*)(den_ws + B_ * K_);

    // d_ws is poisoned 0xAA before every timed call — zero accumulators + ticket.
    hipMemsetAsync(d_ws, 0, (size_t)(B_ * KM + B_ * K_ + 1) * sizeof(float), stream);

    fused_kernel<<<GRID_, TPB, 0, stream>>>(pred, inp, heart, mu_data,
                                            num_ws, den_ws, counter, out);
}

// Round 2
// 149.738 us; speedup vs baseline: 3.1164x; 3.1164x over previous
//
#include <hip/hip_runtime.h>

// Problem constants (fixed by reference setup_inputs)
#define B_     64
#define K_     4
#define M_     3
#define NPIX   65536      // X*Y = 256*256
#define CHUNKS 32         // blocks per image -> grid = 2048 = 8 blocks/CU
#define GRID_  (B_ * CHUNKS)
#define TPB    256
#define ITERS  2          // pixels/thread = ITERS*4 = 8
#define NV     16         // 4 den + 12 num partials per thread
#define KM     (K_ * M_)

// Streaming masked reduction. Each block writes its 16 partial sums to a
// PRIVATE slot ws[blockIdx.x][16] — no atomics, no zeroing needed (poison-safe:
// every slot is overwritten), cross-dispatch visibility via kernel boundary.
__global__ __launch_bounds__(TPB) void partial_kernel(
    const float* __restrict__ pred,    // [B,K,NPIX]
    const float* __restrict__ inp,     // [B,M,NPIX]
    const int*   __restrict__ heart,   // [B,NPIX]
    float* __restrict__ ws)            // [GRID_,NV]
{
    const int b     = blockIdx.x >> 5;           // / CHUNKS
    const int chunk = blockIdx.x & (CHUNKS - 1);

    // val[0..3] = den[k]; val[4 + k*3 + m] = num[k][m]
    float val[NV];
#pragma unroll
    for (int i = 0; i < NV; ++i) val[i] = 0.0f;

#pragma unroll
    for (int it = 0; it < ITERS; ++it) {
        const int pix = chunk * (NPIX / CHUNKS) + it * (TPB * 4) + (int)threadIdx.x * 4;

        const int4 h = *reinterpret_cast<const int4*>(heart + (size_t)b * NPIX + pix);
        float4 mask;
        mask.x = (h.x == 1) ? 1.0f : 0.0f;
        mask.y = (h.y == 1) ? 1.0f : 0.0f;
        mask.z = (h.z == 1) ? 1.0f : 0.0f;
        mask.w = (h.w == 1) ? 1.0f : 0.0f;

        float4 in[M_];
#pragma unroll
        for (int m = 0; m < M_; ++m)
            in[m] = *reinterpret_cast<const float4*>(inp + ((size_t)b * M_ + m) * NPIX + pix);

#pragma unroll
        for (int k = 0; k < K_; ++k) {
            float4 p = *reinterpret_cast<const float4*>(pred + ((size_t)b * K_ + k) * NPIX + pix);
            float4 pm;
            pm.x = p.x * mask.x; pm.y = p.y * mask.y;
            pm.z = p.z * mask.z; pm.w = p.w * mask.w;
            val[k] += (pm.x + pm.y) + (pm.z + pm.w);
#pragma unroll
            for (int m = 0; m < M_; ++m)
                val[4 + k * M_ + m] += pm.x * in[m].x + pm.y * in[m].y
                                     + pm.z * in[m].z + pm.w * in[m].w;
        }
    }

    // 2-stage butterfly (off 32,16): lanes 0..15 hold sums over lane≡l (mod 16).
    // 32 DS ops/wave instead of the original 96; LDS finishes the rest.
#pragma unroll
    for (int off = 32; off >= 16; off >>= 1) {
#pragma unroll
        for (int i = 0; i < NV; ++i)
            val[i] += __shfl_down(val[i], off, 64);
    }

    __shared__ float smem[TPB / 64][16][NV + 1];   // +1 pad: conflict-free writes
    const int lane = threadIdx.x & 63;
    const int wave = threadIdx.x >> 6;
    if (lane < 16) {
#pragma unroll
        for (int i = 0; i < NV; ++i) smem[wave][lane][i] = val[i];
    }
    __syncthreads();

    if (threadIdx.x < NV) {
        float s = 0.0f;
#pragma unroll
        for (int w = 0; w < TPB / 64; ++w)
#pragma unroll
            for (int l = 0; l < 16; ++l)
                s += smem[w][l][threadIdx.x];
        ws[(size_t)blockIdx.x * NV + threadIdx.x] = s;   // private slot, no atomic
    }
}

// One block. Phase 1: 256 threads reduce ws[2048][16] over chunks (float4 along
// the 16-value axis). Phase 2: one wave, lane b owns batch b, shuffle-reduce.
__global__ __launch_bounds__(256) void finalize_kernel(
    const float* __restrict__ ws,       // [B*CHUNKS,NV]
    const float* __restrict__ mu_data,  // [K,M]
    float* __restrict__ out)            // [1]
{
    __shared__ float sums[B_][NV];      // 4 KB
    const int t = threadIdx.x;

    // 256 threads == 64 b × 4 float4-groups: thread owns (b, i4)
    {
        const int b  = t >> 2;
        const int i4 = (t & 3) * 4;
        float4 acc = make_float4(0.f, 0.f, 0.f, 0.f);
        for (int c = 0; c < CHUNKS; ++c) {
            const float4 v = *reinterpret_cast<const float4*>(
                ws + ((size_t)(b * CHUNKS + c) * NV + i4));
            acc.x += v.x; acc.y += v.y; acc.z += v.z; acc.w += v.w;
        }
        sums[b][i4 + 0] = acc.x;
        sums[b][i4 + 1] = acc.y;
        sums[b][i4 + 2] = acc.z;
        sums[b][i4 + 3] = acc.w;
    }
    __syncthreads();

    if (t < B_) {                        // one wave: lane b owns batch element b
        const int b = t;
        float r[KM];
#pragma unroll
        for (int k = 0; k < K_; ++k) {
            const float inv = 1.0f / (sums[b][k] + 1e-10f);
#pragma unroll
            for (int m = 0; m < M_; ++m)
                r[k * M_ + m] = sums[b][K_ + k * M_ + m] * inv;
        }
#pragma unroll
        for (int off = 32; off > 0; off >>= 1) {
#pragma unroll
            for (int i = 0; i < KM; ++i)
                r[i] += __shfl_down(r[i], off, 64);
        }
        if (b == 0) {
            float s = 0.0f;
#pragma unroll
            for (int i = 0; i < KM; ++i) {
                const float d = mu_data[i] - r[i] * (1.0f / (float)B_);
                s += d * d;
            }
            out[0] = s;
        }
    }
}

extern "C" void kernel_launch(void* const* d_in, const int* in_sizes, int n_in,
                              void* d_out, int out_size, void* d_ws, size_t ws_size,
                              hipStream_t stream) {
    const float* pred    = (const float*)d_in[0];  // [64,4,256,256] f32
    const float* inp     = (const float*)d_in[1];  // [64,3,256,256] f32
    const int*   heart   = (const int*)d_in[2];    // [64,1,256,256] i32
    const float* mu_data = (const float*)d_in[3];  // [4,3] f32
    float* out = (float*)d_out;

    float* ws = (float*)d_ws;                      // [GRID_][NV] = 128 KB

    partial_kernel<<<GRID_, TPB, 0, stream>>>(pred, inp, heart, ws);
    finalize_kernel<<<1, 256, 0, stream>>>(ws, mu_data, out);
}

// Round 3
// 145.126 us; speedup vs baseline: 3.2155x; 1.0318x over previous
//
#include <hip/hip_runtime.h>

// Problem constants (fixed by reference setup_inputs)
#define B_     64
#define K_     4
#define M_     3
#define NPIX   65536      // X*Y = 256*256
#define CHUNKS 32         // blocks per image -> grid = 2048 = 8 blocks/CU
#define GRID_  (B_ * CHUNKS)
#define TPB    256
#define ITERS  2          // pixels/thread = ITERS*4 = 8
#define NV     16         // 4 den + 12 num partials per thread
#define KM     (K_ * M_)

typedef float f32x4 __attribute__((ext_vector_type(4)));
typedef int   i32x4 __attribute__((ext_vector_type(4)));

// Streaming masked reduction. All input loads are NON-TEMPORAL: inputs are
// single-use per iteration, and keeping them OUT of the MALL lets the harness's
// 256 MB d_ws poison stay dirty-resident there (overwritten in place each
// iteration) instead of writing back to HBM during this kernel. Theory: the
// poison writeback was stealing ~70% of HBM BW (round-2 counters: 1.6 TB/s
// read share, FETCH only 65 of 128 MB).
__global__ __launch_bounds__(TPB) void partial_kernel(
    const float* __restrict__ pred,    // [B,K,NPIX]
    const float* __restrict__ inp,     // [B,M,NPIX]
    const int*   __restrict__ heart,   // [B,NPIX]
    float* __restrict__ ws)            // [GRID_,NV]
{
    const int b     = blockIdx.x >> 5;           // / CHUNKS
    const int chunk = blockIdx.x & (CHUNKS - 1);

    // val[0..3] = den[k]; val[4 + k*3 + m] = num[k][m]
    float val[NV];
#pragma unroll
    for (int i = 0; i < NV; ++i) val[i] = 0.0f;

#pragma unroll
    for (int it = 0; it < ITERS; ++it) {
        const int pix = chunk * (NPIX / CHUNKS) + it * (TPB * 4) + (int)threadIdx.x * 4;

        const i32x4 h = __builtin_nontemporal_load(
            reinterpret_cast<const i32x4*>(heart + (size_t)b * NPIX + pix));
        float mx = (h.x == 1) ? 1.0f : 0.0f;
        float my = (h.y == 1) ? 1.0f : 0.0f;
        float mz = (h.z == 1) ? 1.0f : 0.0f;
        float mw = (h.w == 1) ? 1.0f : 0.0f;

        f32x4 in[M_];
#pragma unroll
        for (int m = 0; m < M_; ++m)
            in[m] = __builtin_nontemporal_load(
                reinterpret_cast<const f32x4*>(inp + ((size_t)b * M_ + m) * NPIX + pix));

#pragma unroll
        for (int k = 0; k < K_; ++k) {
            const f32x4 p = __builtin_nontemporal_load(
                reinterpret_cast<const f32x4*>(pred + ((size_t)b * K_ + k) * NPIX + pix));
            f32x4 pm;
            pm.x = p.x * mx; pm.y = p.y * my;
            pm.z = p.z * mz; pm.w = p.w * mw;
            val[k] += (pm.x + pm.y) + (pm.z + pm.w);
#pragma unroll
            for (int m = 0; m < M_; ++m)
                val[4 + k * M_ + m] += pm.x * in[m].x + pm.y * in[m].y
                                     + pm.z * in[m].z + pm.w * in[m].w;
        }
    }

    // 2-stage butterfly (off 32,16): lanes 0..15 hold sums over lane≡l (mod 16).
#pragma unroll
    for (int off = 32; off >= 16; off >>= 1) {
#pragma unroll
        for (int i = 0; i < NV; ++i)
            val[i] += __shfl_down(val[i], off, 64);
    }

    __shared__ float smem[TPB / 64][16][NV + 1];   // +1 pad: conflict-free writes
    const int lane = threadIdx.x & 63;
    const int wave = threadIdx.x >> 6;
    if (lane < 16) {
#pragma unroll
        for (int i = 0; i < NV; ++i) smem[wave][lane][i] = val[i];
    }
    __syncthreads();

    if (threadIdx.x < NV) {
        float s = 0.0f;
#pragma unroll
        for (int w = 0; w < TPB / 64; ++w)
#pragma unroll
            for (int l = 0; l < 16; ++l)
                s += smem[w][l][threadIdx.x];
        ws[(size_t)blockIdx.x * NV + threadIdx.x] = s;   // private slot, no atomic
    }
}

// One block. Phase 1: 256 threads reduce ws[2048][16] over chunks (float4 along
// the 16-value axis). Phase 2: one wave, lane b owns batch b, shuffle-reduce.
__global__ __launch_bounds__(256) void finalize_kernel(
    const float* __restrict__ ws,       // [B*CHUNKS,NV]
    const float* __restrict__ mu_data,  // [K,M]
    float* __restrict__ out)            // [1]
{
    __shared__ float sums[B_][NV];      // 4 KB
    const int t = threadIdx.x;

    // 256 threads == 64 b × 4 float4-groups: thread owns (b, i4)
    {
        const int b  = t >> 2;
        const int i4 = (t & 3) * 4;
        float4 acc = make_float4(0.f, 0.f, 0.f, 0.f);
        for (int c = 0; c < CHUNKS; ++c) {
            const float4 v = *reinterpret_cast<const float4*>(
                ws + ((size_t)(b * CHUNKS + c) * NV + i4));
            acc.x += v.x; acc.y += v.y; acc.z += v.z; acc.w += v.w;
        }
        sums[b][i4 + 0] = acc.x;
        sums[b][i4 + 1] = acc.y;
        sums[b][i4 + 2] = acc.z;
        sums[b][i4 + 3] = acc.w;
    }
    __syncthreads();

    if (t < B_) {                        // one wave: lane b owns batch element b
        const int b = t;
        float r[KM];
#pragma unroll
        for (int k = 0; k < K_; ++k) {
            const float inv = 1.0f / (sums[b][k] + 1e-10f);
#pragma unroll
            for (int m = 0; m < M_; ++m)
                r[k * M_ + m] = sums[b][K_ + k * M_ + m] * inv;
        }
#pragma unroll
        for (int off = 32; off > 0; off >>= 1) {
#pragma unroll
            for (int i = 0; i < KM; ++i)
                r[i] += __shfl_down(r[i], off, 64);
        }
        if (b == 0) {
            float s = 0.0f;
#pragma unroll
            for (int i = 0; i < KM; ++i) {
                const float d = mu_data[i] - r[i] * (1.0f / (float)B_);
                s += d * d;
            }
            out[0] = s;
        }
    }
}

extern "C" void kernel_launch(void* const* d_in, const int* in_sizes, int n_in,
                              void* d_out, int out_size, void* d_ws, size_t ws_size,
                              hipStream_t stream) {
    const float* pred    = (const float*)d_in[0];  // [64,4,256,256] f32
    const float* inp     = (const float*)d_in[1];  // [64,3,256,256] f32
    const int*   heart   = (const int*)d_in[2];    // [64,1,256,256] i32
    const float* mu_data = (const float*)d_in[3];  // [4,3] f32
    float* out = (float*)d_out;

    float* ws = (float*)d_ws;                      // [GRID_][NV] = 128 KB

    partial_kernel<<<GRID_, TPB, 0, stream>>>(pred, inp, heart, ws);
    finalize_kernel<<<1, 256, 0, stream>>>(ws, mu_data, out);
}